// Round 2
// baseline (1101.063 us; speedup 1.0000x reference)
//
#include <hip/hip_runtime.h>

// ---------- types ----------
typedef short  short8 __attribute__((ext_vector_type(8)));
typedef __bf16 bf16x8 __attribute__((ext_vector_type(8)));
typedef float  f32x4  __attribute__((ext_vector_type(4)));

__device__ __forceinline__ float bf2f(short s) {
    unsigned u = ((unsigned)(unsigned short)s) << 16;
    return __builtin_bit_cast(float, u);
}
__device__ __forceinline__ short f2bf(float f) {
    unsigned u = __builtin_bit_cast(unsigned, f);
    u += 0x7fffu + ((u >> 16) & 1u);   // RNE
    return (short)(u >> 16);
}
__device__ __forceinline__ f32x4 mfma16(short8 a, short8 b, f32x4 c) {
    return __builtin_amdgcn_mfma_f32_16x16x32_bf16(
        __builtin_bit_cast(bf16x8, a), __builtin_bit_cast(bf16x8, b), c, 0, 0, 0);
}

// Geometry: B=8, H=W=64, C=256, CQ=64
// x NHWC: idx = ((b*64+h)*64+w)*256 + c

// ---------- 0. dtype detect: fp32 low-mantissa shorts are exponent-random ----------
__global__ __launch_bounds__(256) void detect_k(const short* x, int* flag)
{
    __shared__ int red[256];
    int t = threadIdx.x;
    int cnt = 0;
    for (int i = t; i < 4096; i += 256) {
        int e = (x[2 * i] >> 7) & 0xFF;
        cnt += (e >= 100 && e <= 140) ? 1 : 0;   // bf16 N(0,1): ~always; fp32 junk: ~16%
    }
    red[t] = cnt; __syncthreads();
    for (int s = 128; s > 0; s >>= 1) { if (t < s) red[t] += red[t + s]; __syncthreads(); }
    if (t == 0) *flag = (red[0] < 3277) ? 1 : 0;   // 1 => inputs are fp32
}

// ---------- 1. weight repack + bias concat (dtype-branched) ----------
struct Ptrs {
    const void *wq, *wq1, *wq2, *wq3, *wq4, *wk, *wv;
    const void *bq, *bq1, *bq2, *bq3, *bq4, *bk, *bv, *gm;
};

__global__ __launch_bounds__(256) void convert_k(Ptrs P, short* wp, short* bb, const int* flagp)
{
    int f32 = *flagp;
    int idx = blockIdx.x * 256 + threadIdx.x;
    if (idx < 1179648) {
        const void* src; int Cout, base;
        if      (idx <   16384) { src = P.wq;  Cout =  64; base = 0; }
        else if (idx <  163840) { src = P.wq1; Cout =  64; base = 16384; }
        else if (idx <  311296) { src = P.wq2; Cout =  64; base = 163840; }
        else if (idx <  458752) { src = P.wq3; Cout =  64; base = 311296; }
        else if (idx <  524288) { src = P.wq4; Cout = 256; base = 458752; }
        else if (idx < 1114112) { src = P.wk;  Cout = 256; base = 524288; }
        else                    { src = P.wv;  Cout = 256; base = 1114112; }
        int rem = idx - base;
        int t   = rem / (Cout * 256);
        int r2  = rem - t * Cout * 256;
        int co  = r2 >> 8;
        int ci  = r2 & 255;
        int si  = (t * 256 + ci) * Cout + co;   // HWIO source index
        wp[idx] = f32 ? f2bf(((const float*)src)[si]) : ((const short*)src)[si];
    } else if (idx < 1179648 + 1025) {
        int j = idx - 1179648;
        const void* src; int off;
        if      (j <   64) { src = P.bq;  off = j; }
        else if (j <  128) { src = P.bq1; off = j - 64; }
        else if (j <  192) { src = P.bq2; off = j - 128; }
        else if (j <  256) { src = P.bq3; off = j - 192; }
        else if (j <  512) { src = P.bq4; off = j - 256; }
        else if (j <  768) { src = P.bk;  off = j - 512; }
        else if (j < 1024) { src = P.bv;  off = j - 768; }
        else               { src = P.gm;  off = 0; }
        bb[j] = f32 ? f2bf(((const float*)src)[off]) : ((const short*)src)[off];
    }
}

// ---------- 2. generic conv (implicit GEMM, MFMA) ----------
struct ConvJob {
    const void*  src;   // NHWC, Cin=256 (bf16, or fp32 when xdt && flag)
    short*       dst;   // NHWC bf16, stride 256 channels
    const short* wp;    // packed [t][co][ci] bf16
    const short* bias;  // bf16
    int Cout;           // 64 or 256
    int dil;
    int ntaps;          // 1 or 9
    int coff;           // dst channel offset
    int xdt;            // src may be fp32 (is original input x)
};

__global__ __launch_bounds__(256) void conv_mfma(ConvJob j0, ConvJob j1, ConvJob j2, ConvJob j3,
                                                 const int* flagp)
{
    ConvJob J = j0;
    int jy = blockIdx.y;
    if (jy == 1) J = j1; else if (jy == 2) J = j2; else if (jy == 3) J = j3;
    int f32src = J.xdt && (*flagp != 0);

    int wid  = threadIdx.x >> 6;
    int lane = threadIdx.x & 63;
    int g    = blockIdx.x * 4 + wid;
    int ntn  = J.Cout >> 6;                 // 1 or 4 n-tiles
    if (g >= 512 * ntn) return;
    int nt = g & (ntn - 1);
    int pt = (ntn == 4) ? (g >> 2) : g;     // row tile: b,h
    int b  = pt >> 6, h = pt & 63;

    int lrow = lane & 15;
    int q8   = (lane >> 4) << 3;

    f32x4 acc[4][4] = {};
    int nco[4];
#pragma unroll
    for (int ni = 0; ni < 4; ni++) nco[ni] = nt * 64 + ni * 16 + lrow;

    const short8 z8 = {};

    for (int t = 0; t < J.ntaps; ++t) {
        int dy = 0, dx = 0;
        if (J.ntaps == 9) { dy = (t / 3 - 1) * J.dil; dx = (t % 3 - 1) * J.dil; }
        int hh = h + dy;
        bool rv = ((unsigned)hh) < 64u;
        int aoff[4]; bool am[4];
#pragma unroll
        for (int mi = 0; mi < 4; mi++) {
            int ww = mi * 16 + lrow + dx;
            am[mi]   = rv && (((unsigned)ww) < 64u);
            aoff[mi] = am[mi] ? (((b * 64 + hh) * 64 + ww) * 256 + q8) : 0;
        }
        const short* wb = J.wp + (size_t)t * J.Cout * 256 + q8;
#pragma unroll
        for (int kc = 0; kc < 8; ++kc) {
            short8 a[4], bb4[4];
            if (f32src) {
                const float* fs = (const float*)J.src;
#pragma unroll
                for (int mi = 0; mi < 4; mi++) {
                    const float* p = fs + aoff[mi] + kc * 32;
                    short8 v;
#pragma unroll
                    for (int jj = 0; jj < 8; jj++) v[jj] = f2bf(p[jj]);
                    a[mi] = am[mi] ? v : z8;
                }
            } else {
                const short* ss = (const short*)J.src;
#pragma unroll
                for (int mi = 0; mi < 4; mi++) {
                    short8 v = *(const short8*)(ss + aoff[mi] + kc * 32);
                    a[mi] = am[mi] ? v : z8;
                }
            }
#pragma unroll
            for (int ni = 0; ni < 4; ni++)
                bb4[ni] = *(const short8*)(wb + (size_t)nco[ni] * 256 + kc * 32);
#pragma unroll
            for (int mi = 0; mi < 4; mi++)
#pragma unroll
                for (int ni = 0; ni < 4; ni++)
                    acc[mi][ni] = mfma16(a[mi], bb4[ni], acc[mi][ni]);
        }
    }

    int rq = (lane >> 4) * 4;
#pragma unroll
    for (int ni = 0; ni < 4; ni++) {
        int co = nco[ni];
        float bv = bf2f(J.bias[co]);
#pragma unroll
        for (int mi = 0; mi < 4; mi++) {
            int posbase = pt * 64 + mi * 16 + rq;
#pragma unroll
            for (int r = 0; r < 4; r++)
                J.dst[(size_t)(posbase + r) * 256 + J.coff + co] = f2bf(acc[mi][ni][r] + bv);
        }
    }
}

// ---------- 3. energy: Et[b,c,w,i] = sum_j k[b,i,j,c] * q[b,j,w,c] (fp32) ----------
__global__ __launch_bounds__(256) void energy_mfma(const short* q, const short* k, float* Et)
{
    int wid  = threadIdx.x >> 6;
    int lane = threadIdx.x & 63;
    int g = blockIdx.x * 4 + wid;           // 0..2047
    int b = g >> 8, c = g & 255;
    int lrow = lane & 15;
    int q8   = (lane >> 4) << 3;

    f32x4 acc[4][4] = {};
#pragma unroll
    for (int ks = 0; ks < 2; ++ks) {
        int j0 = ks * 32 + q8;
        short8 A[4], Bv[4];
#pragma unroll
        for (int mi = 0; mi < 4; mi++) {
            int w = mi * 16 + lrow;
            const short* p = q + ((size_t)(b * 64 + j0) * 64 + w) * 256 + c;
            short8 v;
#pragma unroll
            for (int jj = 0; jj < 8; jj++) v[jj] = p[(size_t)jj * 16384];
            A[mi] = v;
        }
#pragma unroll
        for (int ni = 0; ni < 4; ni++) {
            int i = ni * 16 + lrow;
            const short* p = k + ((size_t)(b * 64 + i) * 64 + j0) * 256 + c;
            short8 v;
#pragma unroll
            for (int jj = 0; jj < 8; jj++) v[jj] = p[(size_t)jj * 256];
            Bv[ni] = v;
        }
#pragma unroll
        for (int mi = 0; mi < 4; mi++)
#pragma unroll
            for (int ni = 0; ni < 4; ni++)
                acc[mi][ni] = mfma16(A[mi], Bv[ni], acc[mi][ni]);
    }
    int rq = (lane >> 4) * 4;
#pragma unroll
    for (int mi = 0; mi < 4; mi++)
#pragma unroll
        for (int r = 0; r < 4; r++) {
            int w = mi * 16 + rq + r;
            float* row = Et + ((size_t)(b * 256 + c) * 64 + w) * 64;
#pragma unroll
            for (int ni = 0; ni < 4; ni++)
                row[ni * 16 + lrow] = acc[mi][ni][r];
        }
}

// ---------- 4. softmax over c ----------
__global__ __launch_bounds__(256) void softmax_k(const float* Et, short* att)
{
    __shared__ float S[256 * 33];
    __shared__ float red[256];
    __shared__ float sm[256];
    int t  = threadIdx.x;
    int b  = blockIdx.x >> 7;
    int a  = (blockIdx.x >> 1) & 63;
    int jh = blockIdx.x & 1;

    const float* row = Et + ((size_t)(b * 256 + t) * 64 + a) * 64 + jh * 32;
#pragma unroll
    for (int jj = 0; jj < 32; jj += 4) {
        f32x4 v = *(const f32x4*)(row + jj);
#pragma unroll
        for (int l = 0; l < 4; l++) S[t * 33 + jj + l] = v[l];
    }
    __syncthreads();

    int tj = t & 31, tg = t >> 5;
    float m = -1e30f;
#pragma unroll
    for (int cc = 0; cc < 32; ++cc) m = fmaxf(m, S[(tg * 32 + cc) * 33 + tj]);
    red[t] = m;
    __syncthreads();
    if (tg == 0) {
        float mm = red[tj];
#pragma unroll
        for (int gg = 1; gg < 8; ++gg) mm = fmaxf(mm, red[gg * 32 + tj]);
        red[tj] = mm;
    }
    __syncthreads();
    float M = red[tj];
    float s = 0.f;
#pragma unroll
    for (int cc = 0; cc < 32; ++cc) {
        int id = (tg * 32 + cc) * 33 + tj;
        float e = __expf(S[id] - M);
        S[id] = e; s += e;
    }
    sm[t] = s;
    __syncthreads();
    if (tg == 0) {
        float ss = sm[tj];
#pragma unroll
        for (int gg = 1; gg < 8; ++gg) ss += sm[gg * 32 + tj];
        sm[tj] = 1.0f / ss;
    }
    __syncthreads();

    short* orow = att + ((size_t)(b * 256 + t) * 64 + a) * 64 + jh * 32;
#pragma unroll
    for (int jj = 0; jj < 32; jj += 8) {
        short8 o;
#pragma unroll
        for (int l = 0; l < 8; l++) o[l] = f2bf(S[t * 33 + jj + l] * sm[jj + l]);
        *(short8*)(orow + jj) = o;
    }
}

// ---------- 5. out einsum: G[b,c,d,a] = sum_j v[b,d,j,c] * Att[b,c,a,j] ----------
__global__ __launch_bounds__(256) void out_mfma(const short* v, const short* att, short* G)
{
    int wid  = threadIdx.x >> 6;
    int lane = threadIdx.x & 63;
    int g = blockIdx.x * 4 + wid;
    int b = g >> 8, c = g & 255;
    int lrow = lane & 15;
    int q8   = (lane >> 4) << 3;

    f32x4 acc[4][4] = {};
#pragma unroll
    for (int ks = 0; ks < 2; ++ks) {
        int j0 = ks * 32 + q8;
        short8 A[4], Bv[4];
#pragma unroll
        for (int mi = 0; mi < 4; mi++) {
            int d = mi * 16 + lrow;
            const short* p = v + ((size_t)(b * 64 + d) * 64 + j0) * 256 + c;
            short8 vv;
#pragma unroll
            for (int jj = 0; jj < 8; jj++) vv[jj] = p[(size_t)jj * 256];
            A[mi] = vv;
        }
#pragma unroll
        for (int ni = 0; ni < 4; ni++) {
            int a = ni * 16 + lrow;
            Bv[ni] = *(const short8*)(att + ((size_t)(b * 256 + c) * 64 + a) * 64 + j0);
        }
#pragma unroll
        for (int mi = 0; mi < 4; mi++)
#pragma unroll
            for (int ni = 0; ni < 4; ni++)
                acc[mi][ni] = mfma16(A[mi], Bv[ni], acc[mi][ni]);
    }
    int rq = (lane >> 4) * 4;
#pragma unroll
    for (int mi = 0; mi < 4; mi++)
#pragma unroll
        for (int r = 0; r < 4; r++) {
            int d = mi * 16 + rq + r;
            short* row = G + ((size_t)(b * 256 + c) * 64 + d) * 64;
#pragma unroll
            for (int ni = 0; ni < 4; ni++)
                row[ni * 16 + lrow] = f2bf(acc[mi][ni][r]);
        }
}

// ---------- 6. final: out[b,p,r,c] = gamma * G[b,c,r,p] + x[b,p,r,c] ----------
__global__ __launch_bounds__(256) void final_k(const short* G, const void* x,
                                               const void* gamma, void* out, const int* flagp)
{
    int f32 = *flagp;
    int t = threadIdx.x;               // = channel c
    int b = blockIdx.x >> 6, r = blockIdx.x & 63;
    const short* grow = G + ((size_t)(b * 256 + t) * 64 + r) * 64;
    short8 gv[8];
#pragma unroll
    for (int p = 0; p < 8; p++) gv[p] = *(const short8*)(grow + p * 8);
    float gm = f32 ? ((const float*)gamma)[0] : bf2f(((const short*)gamma)[0]);
    for (int p = 0; p < 64; p++) {
        size_t off = ((size_t)(b * 64 + p) * 64 + r) * 256 + t;
        float xv = f32 ? ((const float*)x)[off] : bf2f(((const short*)x)[off]);
        float val = gm * bf2f(gv[p >> 3][p & 7]) + xv;
        if (f32) ((float*)out)[off] = val;
        else     ((short*)out)[off] = f2bf(val);
    }
}

// ---------- launch ----------
extern "C" void kernel_launch(void* const* d_in, const int* in_sizes, int n_in,
                              void* d_out, int out_size, void* d_ws, size_t ws_size,
                              hipStream_t stream)
{
    const void* x   = d_in[0];
    Ptrs P{ d_in[1], d_in[3], d_in[5], d_in[7], d_in[9], d_in[11], d_in[13],
            d_in[2], d_in[4], d_in[6], d_in[8], d_in[10], d_in[12], d_in[14], d_in[15] };

    short* ws   = (short*)d_ws;
    short* qcat = ws;                     // 8.4M bf16 each region
    short* k1   = ws + 8388608;
    short* q    = ws + 16777216;
    short* kk   = ws + 25165824;
    short* vv   = ws + 33554432;
    short* wp   = ws + 41943040;          // packed weights, 1179648 elems
    short* bb   = ws + 43122688;          // biases(1024) + gamma(1)
    int*   flag = (int*)(ws + 43123968);
    float* Et   = (float*)d_ws;           // aliases qcat+k1 (dead by then)
    short* att  = q;                      // aliases q (dead after energy)
    short* G    = kk;                     // aliases kk (dead after energy)

    detect_k<<<1, 256, 0, stream>>>((const short*)x, flag);
    convert_k<<<4612, 256, 0, stream>>>(P, wp, bb, flag);

    // 1x1 convs: wq -> qcat[0:64), wv -> v
    ConvJob ja{ x, qcat, wp + 0,       bb + 0,   64,  1, 1, 0,   1 };
    ConvJob jb{ x, vv,   wp + 1114112, bb + 768, 256, 1, 1, 0,   1 };
    conv_mfma<<<dim3(512, 2), 256, 0, stream>>>(ja, jb, ja, ja, flag);

    // 3x3 convs: wq1/wq2/wq3 -> qcat, wk -> k1
    ConvJob j1{ x, qcat, wp + 16384,  bb + 64,  64,  1, 9, 64,  1 };
    ConvJob j2{ x, qcat, wp + 163840, bb + 128, 64,  3, 9, 128, 1 };
    ConvJob j3{ x, qcat, wp + 311296, bb + 192, 64,  6, 9, 192, 1 };
    ConvJob j4{ x, k1,   wp + 524288, bb + 512, 256, 1, 9, 0,   1 };
    conv_mfma<<<dim3(512, 4), 256, 0, stream>>>(j1, j2, j3, j4, flag);

    // q = 1x1(qcat, wq4)
    ConvJob j5{ qcat, q, wp + 458752, bb + 256, 256, 1, 1, 0, 0 };
    conv_mfma<<<dim3(512, 1), 256, 0, stream>>>(j5, j5, j5, j5, flag);

    // k = 3x3(k1, wk)  (same weights applied twice, per reference)
    ConvJob j6{ k1, kk, wp + 524288, bb + 512, 256, 1, 9, 0, 0 };
    conv_mfma<<<dim3(512, 1), 256, 0, stream>>>(j6, j6, j6, j6, flag);

    energy_mfma<<<512, 256, 0, stream>>>(q, kk, Et);
    softmax_k<<<1024, 256, 0, stream>>>(Et, att);
    out_mfma<<<512, 256, 0, stream>>>(vv, att, G);
    final_k<<<512, 256, 0, stream>>>(G, x, d_in[15], d_out, flag);
}

// Round 3
// 950.884 us; speedup vs baseline: 1.1579x; 1.1579x over previous
//
#include <hip/hip_runtime.h>

// ---------- types ----------
typedef short  short8 __attribute__((ext_vector_type(8)));
typedef __bf16 bf16x8 __attribute__((ext_vector_type(8)));
typedef float  f32x4  __attribute__((ext_vector_type(4)));

__device__ __forceinline__ float bf2f(short s) {
    unsigned u = ((unsigned)(unsigned short)s) << 16;
    return __builtin_bit_cast(float, u);
}
__device__ __forceinline__ short f2bf(float f) {
    unsigned u = __builtin_bit_cast(unsigned, f);
    u += 0x7fffu + ((u >> 16) & 1u);   // RNE
    return (short)(u >> 16);
}
__device__ __forceinline__ f32x4 mfma16(short8 a, short8 b, f32x4 c) {
    return __builtin_amdgcn_mfma_f32_16x16x32_bf16(
        __builtin_bit_cast(bf16x8, a), __builtin_bit_cast(bf16x8, b), c, 0, 0, 0);
}

// Geometry: B=8, H=W=64, C=256, CQ=64
// x NHWC: idx = ((b*64+h)*64+w)*256 + c

// ---------- 0. dtype detect: fp32 low-mantissa shorts are exponent-random ----------
__global__ __launch_bounds__(256) void detect_k(const short* x, int* flag)
{
    __shared__ int red[256];
    int t = threadIdx.x;
    int cnt = 0;
    for (int i = t; i < 4096; i += 256) {
        int e = (x[2 * i] >> 7) & 0xFF;
        cnt += (e >= 100 && e <= 140) ? 1 : 0;   // bf16 N(0,1): ~always; fp32 junk: ~16%
    }
    red[t] = cnt; __syncthreads();
    for (int s = 128; s > 0; s >>= 1) { if (t < s) red[t] += red[t + s]; __syncthreads(); }
    if (t == 0) *flag = (red[0] < 3277) ? 1 : 0;   // 1 => inputs are fp32
}

// ---------- 1a. x -> bf16 (8 elems/thread) ----------
__global__ __launch_bounds__(256) void convert_x(const void* x, short* xb, const int* flagp)
{
    int f32 = *flagp;
    size_t i = ((size_t)blockIdx.x * 256 + threadIdx.x) * 8;   // 8.4M elems total
    short8 v;
    if (f32) {
        const float* fs = (const float*)x + i;
        f32x4 a = *(const f32x4*)fs;
        f32x4 b = *(const f32x4*)(fs + 4);
#pragma unroll
        for (int l = 0; l < 4; l++) { v[l] = f2bf(a[l]); v[4 + l] = f2bf(b[l]); }
    } else {
        v = *(const short8*)((const short*)x + i);
    }
    *(short8*)(xb + i) = v;
}

// ---------- 1b. weight repack + bias concat (dtype-branched) ----------
struct Ptrs {
    const void *wq, *wq1, *wq2, *wq3, *wq4, *wk, *wv;
    const void *bq, *bq1, *bq2, *bq3, *bq4, *bk, *bv, *gm;
};

__global__ __launch_bounds__(256) void convert_k(Ptrs P, short* wp, short* bb, const int* flagp)
{
    int f32 = *flagp;
    int idx = blockIdx.x * 256 + threadIdx.x;
    if (idx < 1179648) {
        const void* src; int Cout, base;
        if      (idx <   16384) { src = P.wq;  Cout =  64; base = 0; }
        else if (idx <  163840) { src = P.wq1; Cout =  64; base = 16384; }
        else if (idx <  311296) { src = P.wq2; Cout =  64; base = 163840; }
        else if (idx <  458752) { src = P.wq3; Cout =  64; base = 311296; }
        else if (idx <  524288) { src = P.wq4; Cout = 256; base = 458752; }
        else if (idx < 1114112) { src = P.wk;  Cout = 256; base = 524288; }
        else                    { src = P.wv;  Cout = 256; base = 1114112; }
        int rem = idx - base;
        int t   = rem / (Cout * 256);
        int r2  = rem - t * Cout * 256;
        int co  = r2 >> 8;
        int ci  = r2 & 255;
        int si  = (t * 256 + ci) * Cout + co;   // HWIO source index
        wp[idx] = f32 ? f2bf(((const float*)src)[si]) : ((const short*)src)[si];
    } else if (idx < 1179648 + 1025) {
        int j = idx - 1179648;
        const void* src; int off;
        if      (j <   64) { src = P.bq;  off = j; }
        else if (j <  128) { src = P.bq1; off = j - 64; }
        else if (j <  192) { src = P.bq2; off = j - 128; }
        else if (j <  256) { src = P.bq3; off = j - 192; }
        else if (j <  512) { src = P.bq4; off = j - 256; }
        else if (j <  768) { src = P.bk;  off = j - 512; }
        else if (j < 1024) { src = P.bv;  off = j - 768; }
        else               { src = P.gm;  off = 0; }
        bb[j] = f32 ? f2bf(((const float*)src)[off]) : ((const short*)src)[off];
    }
}

// ---------- 2. fused conv (implicit GEMM, MFMA, job table) ----------
struct ConvJob {
    const short* src;   // NHWC bf16, Cin=256
    short*       dst;   // NHWC bf16, stride 256 channels
    const short* wp;    // packed [t][co][ci] bf16
    const short* bias;  // bf16
    int Cout;           // 64 or 256
    int dil;
    int ntaps;          // 1 or 9
    int coff;           // dst channel offset
};
struct ConvTable { ConvJob j[6]; int end[6]; };

__global__ __launch_bounds__(256) void conv_all(ConvTable T)
{
    int wid  = threadIdx.x >> 6;
    int lane = threadIdx.x & 63;
    int gw   = blockIdx.x * 4 + wid;
    int ji = 0;
    while (ji < 5 && gw >= T.end[ji]) ji++;
    if (gw >= T.end[ji]) return;
    ConvJob J = T.j[ji];
    int g = gw - (ji ? T.end[ji - 1] : 0);

    int ntn = J.Cout >> 6;                  // 1 or 4 n-tiles
    int nt  = g & (ntn - 1);
    int pt  = (ntn == 4) ? (g >> 2) : g;    // row tile: b,h
    int b   = pt >> 6, h = pt & 63;

    int lrow = lane & 15;
    int q8   = (lane >> 4) << 3;

    f32x4 acc[4][4] = {};
    int nco[4];
#pragma unroll
    for (int ni = 0; ni < 4; ni++) nco[ni] = nt * 64 + ni * 16 + lrow;

    const short8 z8 = {};

    for (int t = 0; t < J.ntaps; ++t) {
        int dy = 0, dx = 0;
        if (J.ntaps == 9) { dy = (t / 3 - 1) * J.dil; dx = (t % 3 - 1) * J.dil; }
        int hh = h + dy;
        bool rv = ((unsigned)hh) < 64u;
        int aoff[4]; bool am[4];
#pragma unroll
        for (int mi = 0; mi < 4; mi++) {
            int ww = mi * 16 + lrow + dx;
            am[mi]   = rv && (((unsigned)ww) < 64u);
            aoff[mi] = am[mi] ? (((b * 64 + hh) * 64 + ww) * 256 + q8) : 0;
        }
        const short* wb = J.wp + (size_t)t * J.Cout * 256 + q8;
#pragma unroll
        for (int kc = 0; kc < 8; ++kc) {
            short8 a[4], bb4[4];
#pragma unroll
            for (int mi = 0; mi < 4; mi++) {
                short8 v = *(const short8*)(J.src + aoff[mi] + kc * 32);
                a[mi] = am[mi] ? v : z8;
            }
#pragma unroll
            for (int ni = 0; ni < 4; ni++)
                bb4[ni] = *(const short8*)(wb + (size_t)nco[ni] * 256 + kc * 32);
#pragma unroll
            for (int mi = 0; mi < 4; mi++)
#pragma unroll
                for (int ni = 0; ni < 4; ni++)
                    acc[mi][ni] = mfma16(a[mi], bb4[ni], acc[mi][ni]);
        }
    }

    int rq = (lane >> 4) * 4;
#pragma unroll
    for (int ni = 0; ni < 4; ni++) {
        int co = nco[ni];
        float bv = bf2f(J.bias[co]);
#pragma unroll
        for (int mi = 0; mi < 4; mi++) {
            int posbase = pt * 64 + mi * 16 + rq;
#pragma unroll
            for (int r = 0; r < 4; r++)
                J.dst[(size_t)(posbase + r) * 256 + J.coff + co] = f2bf(acc[mi][ni][r] + bv);
        }
    }
}

// ---------- 3. energy: Et[b,c,w,i] = sum_j k[b,i,j,c] * q[b,j,w,c] (fp32) ----------
__global__ __launch_bounds__(256) void energy_mfma(const short* q, const short* k, float* Et)
{
    int wid  = threadIdx.x >> 6;
    int lane = threadIdx.x & 63;
    int g = blockIdx.x * 4 + wid;           // 0..2047
    int b = g >> 8, c = g & 255;
    int lrow = lane & 15;
    int q8   = (lane >> 4) << 3;

    f32x4 acc[4][4] = {};
#pragma unroll
    for (int ks = 0; ks < 2; ++ks) {
        int j0 = ks * 32 + q8;
        short8 A[4], Bv[4];
#pragma unroll
        for (int mi = 0; mi < 4; mi++) {
            int w = mi * 16 + lrow;
            const short* p = q + ((size_t)(b * 64 + j0) * 64 + w) * 256 + c;
            short8 v;
#pragma unroll
            for (int jj = 0; jj < 8; jj++) v[jj] = p[(size_t)jj * 16384];
            A[mi] = v;
        }
#pragma unroll
        for (int ni = 0; ni < 4; ni++) {
            int i = ni * 16 + lrow;
            const short* p = k + ((size_t)(b * 64 + i) * 64 + j0) * 256 + c;
            short8 v;
#pragma unroll
            for (int jj = 0; jj < 8; jj++) v[jj] = p[(size_t)jj * 256];
            Bv[ni] = v;
        }
#pragma unroll
        for (int mi = 0; mi < 4; mi++)
#pragma unroll
            for (int ni = 0; ni < 4; ni++)
                acc[mi][ni] = mfma16(A[mi], Bv[ni], acc[mi][ni]);
    }
    int rq = (lane >> 4) * 4;
#pragma unroll
    for (int mi = 0; mi < 4; mi++)
#pragma unroll
        for (int r = 0; r < 4; r++) {
            int w = mi * 16 + rq + r;
            float* row = Et + ((size_t)(b * 256 + c) * 64 + w) * 64;
#pragma unroll
            for (int ni = 0; ni < 4; ni++)
                row[ni * 16 + lrow] = acc[mi][ni][r];
        }
}

// ---------- 4. softmax over c ----------
__global__ __launch_bounds__(256) void softmax_k(const float* Et, short* att)
{
    __shared__ float S[256 * 33];
    __shared__ float red[256];
    __shared__ float sm[256];
    int t  = threadIdx.x;
    int b  = blockIdx.x >> 7;
    int a  = (blockIdx.x >> 1) & 63;
    int jh = blockIdx.x & 1;

    const float* row = Et + ((size_t)(b * 256 + t) * 64 + a) * 64 + jh * 32;
#pragma unroll
    for (int jj = 0; jj < 32; jj += 4) {
        f32x4 v = *(const f32x4*)(row + jj);
#pragma unroll
        for (int l = 0; l < 4; l++) S[t * 33 + jj + l] = v[l];
    }
    __syncthreads();

    int tj = t & 31, tg = t >> 5;
    float m = -1e30f;
#pragma unroll
    for (int cc = 0; cc < 32; ++cc) m = fmaxf(m, S[(tg * 32 + cc) * 33 + tj]);
    red[t] = m;
    __syncthreads();
    if (tg == 0) {
        float mm = red[tj];
#pragma unroll
        for (int gg = 1; gg < 8; ++gg) mm = fmaxf(mm, red[gg * 32 + tj]);
        red[tj] = mm;
    }
    __syncthreads();
    float M = red[tj];
    float s = 0.f;
#pragma unroll
    for (int cc = 0; cc < 32; ++cc) {
        int id = (tg * 32 + cc) * 33 + tj;
        float e = __expf(S[id] - M);
        S[id] = e; s += e;
    }
    sm[t] = s;
    __syncthreads();
    if (tg == 0) {
        float ss = sm[tj];
#pragma unroll
        for (int gg = 1; gg < 8; ++gg) ss += sm[gg * 32 + tj];
        sm[tj] = 1.0f / ss;
    }
    __syncthreads();

    short* orow = att + ((size_t)(b * 256 + t) * 64 + a) * 64 + jh * 32;
#pragma unroll
    for (int jj = 0; jj < 32; jj += 8) {
        short8 o;
#pragma unroll
        for (int l = 0; l < 8; l++) o[l] = f2bf(S[t * 33 + jj + l] * sm[jj + l]);
        *(short8*)(orow + jj) = o;
    }
}

// ---------- 5. out einsum: G[b,c,d,a] = sum_j v[b,d,j,c] * Att[b,c,a,j] ----------
__global__ __launch_bounds__(256) void out_mfma(const short* v, const short* att, short* G)
{
    int wid  = threadIdx.x >> 6;
    int lane = threadIdx.x & 63;
    int g = blockIdx.x * 4 + wid;
    int b = g >> 8, c = g & 255;
    int lrow = lane & 15;
    int q8   = (lane >> 4) << 3;

    f32x4 acc[4][4] = {};
#pragma unroll
    for (int ks = 0; ks < 2; ++ks) {
        int j0 = ks * 32 + q8;
        short8 A[4], Bv[4];
#pragma unroll
        for (int mi = 0; mi < 4; mi++) {
            int d = mi * 16 + lrow;
            const short* p = v + ((size_t)(b * 64 + d) * 64 + j0) * 256 + c;
            short8 vv;
#pragma unroll
            for (int jj = 0; jj < 8; jj++) vv[jj] = p[(size_t)jj * 256];
            A[mi] = vv;
        }
#pragma unroll
        for (int ni = 0; ni < 4; ni++) {
            int a = ni * 16 + lrow;
            Bv[ni] = *(const short8*)(att + ((size_t)(b * 256 + c) * 64 + a) * 64 + j0);
        }
#pragma unroll
        for (int mi = 0; mi < 4; mi++)
#pragma unroll
            for (int ni = 0; ni < 4; ni++)
                acc[mi][ni] = mfma16(A[mi], Bv[ni], acc[mi][ni]);
    }
    int rq = (lane >> 4) * 4;
#pragma unroll
    for (int mi = 0; mi < 4; mi++)
#pragma unroll
        for (int r = 0; r < 4; r++) {
            int d = mi * 16 + rq + r;
            short* row = G + ((size_t)(b * 256 + c) * 64 + d) * 64;
#pragma unroll
            for (int ni = 0; ni < 4; ni++)
                row[ni * 16 + lrow] = f2bf(acc[mi][ni][r]);
        }
}

// ---------- 6. final: out[b,p,r,c] = gamma * G[b,c,r,p] + x[b,p,r,c] ----------
__global__ __launch_bounds__(256) void final_k(const short* G, const void* x,
                                               const void* gamma, void* out, const int* flagp)
{
    int f32 = *flagp;
    int t = threadIdx.x;               // = channel c
    int b = blockIdx.x >> 6, r = blockIdx.x & 63;
    const short* grow = G + ((size_t)(b * 256 + t) * 64 + r) * 64;
    short8 gv[8];
#pragma unroll
    for (int p = 0; p < 8; p++) gv[p] = *(const short8*)(grow + p * 8);
    float gm = f32 ? ((const float*)gamma)[0] : bf2f(((const short*)gamma)[0]);
    for (int p = 0; p < 64; p++) {
        size_t off = ((size_t)(b * 64 + p) * 64 + r) * 256 + t;
        float xv = f32 ? ((const float*)x)[off] : bf2f(((const short*)x)[off]);
        float val = gm * bf2f(gv[p >> 3][p & 7]) + xv;
        if (f32) ((float*)out)[off] = val;
        else     ((short*)out)[off] = f2bf(val);
    }
}

// ---------- launch ----------
extern "C" void kernel_launch(void* const* d_in, const int* in_sizes, int n_in,
                              void* d_out, int out_size, void* d_ws, size_t ws_size,
                              hipStream_t stream)
{
    const void* x   = d_in[0];
    Ptrs P{ d_in[1], d_in[3], d_in[5], d_in[7], d_in[9], d_in[11], d_in[13],
            d_in[2], d_in[4], d_in[6], d_in[8], d_in[10], d_in[12], d_in[14], d_in[15] };

    short* ws   = (short*)d_ws;
    short* qcat = ws;                     // R0: 8.4M bf16
    short* k1   = ws + 8388608;           // R1
    short* q    = ws + 16777216;          // R2
    short* kk   = ws + 25165824;          // R3
    short* vv   = ws + 33554432;          // R4
    short* wp   = ws + 41943040;          // packed weights, 1179648 elems
    short* bb   = ws + 43122688;          // biases(1024) + gamma(1)
    int*   flag = (int*)(ws + 43123968);
    short* xb   = q;                      // x as bf16; dead before q is written
    float* Et   = (float*)d_ws;           // aliases R0+R1 (dead by then)
    short* att  = q;                      // aliases R2 (q dead after energy)
    short* G    = kk;                     // aliases R3 (kk dead after energy)

    detect_k<<<1, 256, 0, stream>>>((const short*)x, flag);
    convert_x<<<4096, 256, 0, stream>>>(x, xb, flag);
    convert_k<<<4612, 256, 0, stream>>>(P, wp, bb, flag);

    // dispatch A: all six x-reading convs fused (6144 waves)
    ConvJob ja{ xb, qcat, wp + 0,       bb + 0,   64,  1, 1, 0   };
    ConvJob jb{ xb, vv,   wp + 1114112, bb + 768, 256, 1, 1, 0   };
    ConvJob j1{ xb, qcat, wp + 16384,   bb + 64,  64,  1, 9, 64  };
    ConvJob j2{ xb, qcat, wp + 163840,  bb + 128, 64,  3, 9, 128 };
    ConvJob j3{ xb, qcat, wp + 311296,  bb + 192, 64,  6, 9, 192 };
    ConvJob j4{ xb, k1,   wp + 524288,  bb + 512, 256, 1, 9, 0   };
    ConvTable TA{ { ja, jb, j1, j2, j3, j4 }, { 512, 2560, 3072, 3584, 4096, 6144 } };
    conv_all<<<1536, 256, 0, stream>>>(TA);

    // dispatch B: q = 1x1(qcat, wq4), k = 3x3(k1, wk)  (4096 waves)
    ConvJob j5{ qcat, q, wp + 458752, bb + 256, 256, 1, 1, 0 };
    ConvJob j6{ k1,  kk, wp + 524288, bb + 512, 256, 1, 9, 0 };
    ConvTable TB{ { j5, j6, j6, j6, j6, j6 }, { 2048, 4096, 4096, 4096, 4096, 4096 } };
    conv_all<<<1024, 256, 0, stream>>>(TB);

    energy_mfma<<<512, 256, 0, stream>>>(q, kk, Et);
    softmax_k<<<1024, 256, 0, stream>>>(Et, att);
    out_mfma<<<512, 256, 0, stream>>>(vv, att, G);
    final_k<<<512, 256, 0, stream>>>(G, x, d_in[15], d_out, flag);
}

// Round 4
// 693.581 us; speedup vs baseline: 1.5875x; 1.3710x over previous
//
#include <hip/hip_runtime.h>

// ---------- types ----------
typedef short  short8 __attribute__((ext_vector_type(8)));
typedef __bf16 bf16x8 __attribute__((ext_vector_type(8)));
typedef float  f32x4  __attribute__((ext_vector_type(4)));

__device__ __forceinline__ float bf2f(short s) {
    unsigned u = ((unsigned)(unsigned short)s) << 16;
    return __builtin_bit_cast(float, u);
}
__device__ __forceinline__ short f2bf(float f) {
    unsigned u = __builtin_bit_cast(unsigned, f);
    u += 0x7fffu + ((u >> 16) & 1u);   // RNE
    return (short)(u >> 16);
}
__device__ __forceinline__ f32x4 mfma16(short8 a, short8 b, f32x4 c) {
    return __builtin_amdgcn_mfma_f32_16x16x32_bf16(
        __builtin_bit_cast(bf16x8, a), __builtin_bit_cast(bf16x8, b), c, 0, 0, 0);
}

// Geometry: B=8, H=W=64, C=256, CQ=64
// x NHWC: idx = ((b*64+h)*64+w)*256 + c

// ---------- 0. dtype detect: fp32 low-mantissa shorts are exponent-random ----------
__global__ __launch_bounds__(256) void detect_k(const short* x, int* flag)
{
    __shared__ int red[256];
    int t = threadIdx.x;
    int cnt = 0;
    for (int i = t; i < 4096; i += 256) {
        int e = (x[2 * i] >> 7) & 0xFF;
        cnt += (e >= 100 && e <= 140) ? 1 : 0;   // bf16 N(0,1): ~always; fp32 junk: ~16%
    }
    red[t] = cnt; __syncthreads();
    for (int s = 128; s > 0; s >>= 1) { if (t < s) red[t] += red[t + s]; __syncthreads(); }
    if (t == 0) *flag = (red[0] < 3277) ? 1 : 0;   // 1 => inputs are fp32
}

// ---------- 1a. x -> bf16 (8 elems/thread) ----------
__global__ __launch_bounds__(256) void convert_x(const void* x, short* xb, const int* flagp)
{
    int f32 = *flagp;
    size_t i = ((size_t)blockIdx.x * 256 + threadIdx.x) * 8;   // 8.4M elems total
    short8 v;
    if (f32) {
        const float* fs = (const float*)x + i;
        f32x4 a = *(const f32x4*)fs;
        f32x4 b = *(const f32x4*)(fs + 4);
#pragma unroll
        for (int l = 0; l < 4; l++) { v[l] = f2bf(a[l]); v[4 + l] = f2bf(b[l]); }
    } else {
        v = *(const short8*)((const short*)x + i);
    }
    *(short8*)(xb + i) = v;
}

// ---------- 1b. weight repack + bias concat (dtype-branched) ----------
struct Ptrs {
    const void *wq, *wq1, *wq2, *wq3, *wq4, *wk, *wv;
    const void *bq, *bq1, *bq2, *bq3, *bq4, *bk, *bv, *gm;
};

__global__ __launch_bounds__(256) void convert_k(Ptrs P, short* wp, short* bb, const int* flagp)
{
    int f32 = *flagp;
    int idx = blockIdx.x * 256 + threadIdx.x;
    if (idx < 1179648) {
        const void* src; int Cout, base;
        if      (idx <   16384) { src = P.wq;  Cout =  64; base = 0; }
        else if (idx <  163840) { src = P.wq1; Cout =  64; base = 16384; }
        else if (idx <  311296) { src = P.wq2; Cout =  64; base = 163840; }
        else if (idx <  458752) { src = P.wq3; Cout =  64; base = 311296; }
        else if (idx <  524288) { src = P.wq4; Cout = 256; base = 458752; }
        else if (idx < 1114112) { src = P.wk;  Cout = 256; base = 524288; }
        else                    { src = P.wv;  Cout = 256; base = 1114112; }
        int rem = idx - base;
        int t   = rem / (Cout * 256);
        int r2  = rem - t * Cout * 256;
        int co  = r2 >> 8;
        int ci  = r2 & 255;
        int si  = (t * 256 + ci) * Cout + co;   // HWIO source index
        wp[idx] = f32 ? f2bf(((const float*)src)[si]) : ((const short*)src)[si];
    } else if (idx < 1179648 + 1025) {
        int j = idx - 1179648;
        const void* src; int off;
        if      (j <   64) { src = P.bq;  off = j; }
        else if (j <  128) { src = P.bq1; off = j - 64; }
        else if (j <  192) { src = P.bq2; off = j - 128; }
        else if (j <  256) { src = P.bq3; off = j - 192; }
        else if (j <  512) { src = P.bq4; off = j - 256; }
        else if (j <  768) { src = P.bk;  off = j - 512; }
        else if (j < 1024) { src = P.bv;  off = j - 768; }
        else               { src = P.gm;  off = 0; }
        bb[j] = f32 ? f2bf(((const float*)src)[off]) : ((const short*)src)[off];
    }
}

// ---------- 2. fused conv (implicit GEMM, MFMA, job table) ----------
struct ConvJob {
    const short* src;   // NHWC bf16, Cin=256
    short*       dst;   // NHWC bf16, stride 256 channels
    const short* wp;    // packed [t][co][ci] bf16
    const short* bias;  // bf16
    int Cout;           // 64 or 256
    int dil;
    int ntaps;          // 1 or 9
    int coff;           // dst channel offset
};
struct ConvTable { ConvJob j[6]; int end[6]; };

__global__ __launch_bounds__(256) void conv_all(ConvTable T)
{
    int wid  = threadIdx.x >> 6;
    int lane = threadIdx.x & 63;
    int gw   = blockIdx.x * 4 + wid;
    int ji = 0;
    while (ji < 5 && gw >= T.end[ji]) ji++;
    if (gw >= T.end[ji]) return;
    ConvJob J = T.j[ji];
    int g = gw - (ji ? T.end[ji - 1] : 0);

    int ntn = J.Cout >> 6;                  // 1 or 4 n-tiles
    int nt  = g & (ntn - 1);
    int pt  = (ntn == 4) ? (g >> 2) : g;    // row tile: b,h
    int b   = pt >> 6, h = pt & 63;

    int lrow = lane & 15;
    int q8   = (lane >> 4) << 3;

    f32x4 acc[4][4] = {};
    int nco[4];
#pragma unroll
    for (int ni = 0; ni < 4; ni++) nco[ni] = nt * 64 + ni * 16 + lrow;

    const short8 z8 = {};

    for (int t = 0; t < J.ntaps; ++t) {
        int dy = 0, dx = 0;
        if (J.ntaps == 9) { dy = (t / 3 - 1) * J.dil; dx = (t % 3 - 1) * J.dil; }
        int hh = h + dy;
        bool rv = ((unsigned)hh) < 64u;
        int aoff[4]; bool am[4];
#pragma unroll
        for (int mi = 0; mi < 4; mi++) {
            int ww = mi * 16 + lrow + dx;
            am[mi]   = rv && (((unsigned)ww) < 64u);
            aoff[mi] = am[mi] ? (((b * 64 + hh) * 64 + ww) * 256 + q8) : 0;
        }
        const short* wb = J.wp + (size_t)t * J.Cout * 256 + q8;
#pragma unroll
        for (int kc = 0; kc < 8; ++kc) {
            short8 a[4], bb4[4];
#pragma unroll
            for (int mi = 0; mi < 4; mi++) {
                short8 v = *(const short8*)(J.src + aoff[mi] + kc * 32);
                a[mi] = am[mi] ? v : z8;
            }
#pragma unroll
            for (int ni = 0; ni < 4; ni++)
                bb4[ni] = *(const short8*)(wb + (size_t)nco[ni] * 256 + kc * 32);
#pragma unroll
            for (int mi = 0; mi < 4; mi++)
#pragma unroll
                for (int ni = 0; ni < 4; ni++)
                    acc[mi][ni] = mfma16(a[mi], bb4[ni], acc[mi][ni]);
        }
    }

    int rq = (lane >> 4) * 4;
#pragma unroll
    for (int ni = 0; ni < 4; ni++) {
        int co = nco[ni];
        float bv = bf2f(J.bias[co]);
#pragma unroll
        for (int mi = 0; mi < 4; mi++) {
            int posbase = pt * 64 + mi * 16 + rq;
#pragma unroll
            for (int r = 0; r < 4; r++)
                J.dst[(size_t)(posbase + r) * 256 + J.coff + co] = f2bf(acc[mi][ni][r] + bv);
        }
    }
}

// ---------- 3. energy: Et[b,c,w,i] = sum_j k[b,i,j,c] * q[b,j,w,c] (fp32) ----------
__global__ __launch_bounds__(256) void energy_mfma(const short* q, const short* k, float* Et)
{
    int wid  = threadIdx.x >> 6;
    int lane = threadIdx.x & 63;
    int g = blockIdx.x * 4 + wid;           // 0..2047
    int b = g >> 8, c = g & 255;
    int lrow = lane & 15;
    int q8   = (lane >> 4) << 3;

    f32x4 acc[4][4] = {};
#pragma unroll
    for (int ks = 0; ks < 2; ++ks) {
        int j0 = ks * 32 + q8;
        short8 A[4], Bv[4];
#pragma unroll
        for (int mi = 0; mi < 4; mi++) {
            int w = mi * 16 + lrow;
            const short* p = q + ((size_t)(b * 64 + j0) * 64 + w) * 256 + c;
            short8 v;
#pragma unroll
            for (int jj = 0; jj < 8; jj++) v[jj] = p[(size_t)jj * 16384];
            A[mi] = v;
        }
#pragma unroll
        for (int ni = 0; ni < 4; ni++) {
            int i = ni * 16 + lrow;
            const short* p = k + ((size_t)(b * 64 + i) * 64 + j0) * 256 + c;
            short8 v;
#pragma unroll
            for (int jj = 0; jj < 8; jj++) v[jj] = p[(size_t)jj * 256];
            Bv[ni] = v;
        }
#pragma unroll
        for (int mi = 0; mi < 4; mi++)
#pragma unroll
            for (int ni = 0; ni < 4; ni++)
                acc[mi][ni] = mfma16(A[mi], Bv[ni], acc[mi][ni]);
    }
    int rq = (lane >> 4) * 4;
#pragma unroll
    for (int mi = 0; mi < 4; mi++)
#pragma unroll
        for (int r = 0; r < 4; r++) {
            int w = mi * 16 + rq + r;
            float* row = Et + ((size_t)(b * 256 + c) * 64 + w) * 64;
#pragma unroll
            for (int ni = 0; ni < 4; ni++)
                row[ni * 16 + lrow] = acc[mi][ni][r];
        }
}

// ---------- 4. softmax over c ----------
__global__ __launch_bounds__(256) void softmax_k(const float* Et, short* att)
{
    __shared__ float S[256 * 33];
    __shared__ float red[256];
    __shared__ float sm[256];
    int t  = threadIdx.x;
    int b  = blockIdx.x >> 7;
    int a  = (blockIdx.x >> 1) & 63;
    int jh = blockIdx.x & 1;

    const float* row = Et + ((size_t)(b * 256 + t) * 64 + a) * 64 + jh * 32;
#pragma unroll
    for (int jj = 0; jj < 32; jj += 4) {
        f32x4 v = *(const f32x4*)(row + jj);
#pragma unroll
        for (int l = 0; l < 4; l++) S[t * 33 + jj + l] = v[l];
    }
    __syncthreads();

    int tj = t & 31, tg = t >> 5;
    float m = -1e30f;
#pragma unroll
    for (int cc = 0; cc < 32; ++cc) m = fmaxf(m, S[(tg * 32 + cc) * 33 + tj]);
    red[t] = m;
    __syncthreads();
    if (tg == 0) {
        float mm = red[tj];
#pragma unroll
        for (int gg = 1; gg < 8; ++gg) mm = fmaxf(mm, red[gg * 32 + tj]);
        red[tj] = mm;
    }
    __syncthreads();
    float M = red[tj];
    float s = 0.f;
#pragma unroll
    for (int cc = 0; cc < 32; ++cc) {
        int id = (tg * 32 + cc) * 33 + tj;
        float e = __expf(S[id] - M);
        S[id] = e; s += e;
    }
    sm[t] = s;
    __syncthreads();
    if (tg == 0) {
        float ss = sm[tj];
#pragma unroll
        for (int gg = 1; gg < 8; ++gg) ss += sm[gg * 32 + tj];
        sm[tj] = 1.0f / ss;
    }
    __syncthreads();

    short* orow = att + ((size_t)(b * 256 + t) * 64 + a) * 64 + jh * 32;
#pragma unroll
    for (int jj = 0; jj < 32; jj += 8) {
        short8 o;
#pragma unroll
        for (int l = 0; l < 8; l++) o[l] = f2bf(S[t * 33 + jj + l] * sm[jj + l]);
        *(short8*)(orow + jj) = o;
    }
}

// ---------- 5. out einsum: G[b,c,d,a] = sum_j v[b,d,j,c] * Att[b,c,a,j] ----------
__global__ __launch_bounds__(256) void out_mfma(const short* v, const short* att, short* G)
{
    int wid  = threadIdx.x >> 6;
    int lane = threadIdx.x & 63;
    int g = blockIdx.x * 4 + wid;
    int b = g >> 8, c = g & 255;
    int lrow = lane & 15;
    int q8   = (lane >> 4) << 3;

    f32x4 acc[4][4] = {};
#pragma unroll
    for (int ks = 0; ks < 2; ++ks) {
        int j0 = ks * 32 + q8;
        short8 A[4], Bv[4];
#pragma unroll
        for (int mi = 0; mi < 4; mi++) {
            int d = mi * 16 + lrow;
            const short* p = v + ((size_t)(b * 64 + d) * 64 + j0) * 256 + c;
            short8 vv;
#pragma unroll
            for (int jj = 0; jj < 8; jj++) vv[jj] = p[(size_t)jj * 256];
            A[mi] = vv;
        }
#pragma unroll
        for (int ni = 0; ni < 4; ni++) {
            int a = ni * 16 + lrow;
            Bv[ni] = *(const short8*)(att + ((size_t)(b * 256 + c) * 64 + a) * 64 + j0);
        }
#pragma unroll
        for (int mi = 0; mi < 4; mi++)
#pragma unroll
            for (int ni = 0; ni < 4; ni++)
                acc[mi][ni] = mfma16(A[mi], Bv[ni], acc[mi][ni]);
    }
    int rq = (lane >> 4) * 4;
#pragma unroll
    for (int mi = 0; mi < 4; mi++)
#pragma unroll
        for (int r = 0; r < 4; r++) {
            int d = mi * 16 + rq + r;
            short* row = G + ((size_t)(b * 256 + c) * 64 + d) * 64;
#pragma unroll
            for (int ni = 0; ni < 4; ni++)
                row[ni * 16 + lrow] = f2bf(acc[mi][ni][r]);
        }
}

// ---------- 6. final: out[b,p,r,c] = gamma * G[b,c,r,p] + x[b,p,r,c] ----------
// NOTE: no cross-thread exchange needed (thread t=c consumes the row it loads).
// The p-loop is structured so every vector extract has a CONSTANT index —
// dynamic indexing into a register array demotes it to scratch (was 296 us).
__global__ __launch_bounds__(256) void final_k(const short* G, const void* x,
                                               const void* gamma, void* out, const int* flagp)
{
    int f32 = *flagp;
    int t = threadIdx.x;               // = channel c
    int b = blockIdx.x >> 6, r = blockIdx.x & 63;
    const short* grow = G + ((size_t)(b * 256 + t) * 64 + r) * 64;
    float gm = f32 ? ((const float*)gamma)[0] : bf2f(((const short*)gamma)[0]);
    size_t obase = ((size_t)(b * 64) * 64 + r) * 256 + t;   // p=0 offset; p stride 16384
    if (f32) {
        const float* xs = (const float*)x;
        float* os = (float*)out;
#pragma unroll
        for (int p8 = 0; p8 < 8; p8++) {
            short8 gv = *(const short8*)(grow + p8 * 8);
#pragma unroll
            for (int l = 0; l < 8; l++) {
                size_t off = obase + (size_t)(p8 * 8 + l) * 16384;
                os[off] = gm * bf2f(gv[l]) + xs[off];
            }
        }
    } else {
        const short* xs = (const short*)x;
        short* os = (short*)out;
#pragma unroll
        for (int p8 = 0; p8 < 8; p8++) {
            short8 gv = *(const short8*)(grow + p8 * 8);
#pragma unroll
            for (int l = 0; l < 8; l++) {
                size_t off = obase + (size_t)(p8 * 8 + l) * 16384;
                os[off] = f2bf(gm * bf2f(gv[l]) + bf2f(xs[off]));
            }
        }
    }
}

// ---------- launch ----------
extern "C" void kernel_launch(void* const* d_in, const int* in_sizes, int n_in,
                              void* d_out, int out_size, void* d_ws, size_t ws_size,
                              hipStream_t stream)
{
    const void* x   = d_in[0];
    Ptrs P{ d_in[1], d_in[3], d_in[5], d_in[7], d_in[9], d_in[11], d_in[13],
            d_in[2], d_in[4], d_in[6], d_in[8], d_in[10], d_in[12], d_in[14], d_in[15] };

    short* ws   = (short*)d_ws;
    short* qcat = ws;                     // R0: 8.4M bf16
    short* k1   = ws + 8388608;           // R1
    short* q    = ws + 16777216;          // R2
    short* kk   = ws + 25165824;          // R3
    short* vv   = ws + 33554432;          // R4
    short* wp   = ws + 41943040;          // packed weights, 1179648 elems
    short* bb   = ws + 43122688;          // biases(1024) + gamma(1)
    int*   flag = (int*)(ws + 43123968);
    short* xb   = q;                      // x as bf16; dead before q is written
    float* Et   = (float*)d_ws;           // aliases R0+R1 (dead by then)
    short* att  = q;                      // aliases R2 (q dead after energy)
    short* G    = kk;                     // aliases R3 (kk dead after energy)

    detect_k<<<1, 256, 0, stream>>>((const short*)x, flag);
    convert_x<<<4096, 256, 0, stream>>>(x, xb, flag);
    convert_k<<<4612, 256, 0, stream>>>(P, wp, bb, flag);

    // dispatch A: all six x-reading convs fused (6144 waves)
    ConvJob ja{ xb, qcat, wp + 0,       bb + 0,   64,  1, 1, 0   };
    ConvJob jb{ xb, vv,   wp + 1114112, bb + 768, 256, 1, 1, 0   };
    ConvJob j1{ xb, qcat, wp + 16384,   bb + 64,  64,  1, 9, 64  };
    ConvJob j2{ xb, qcat, wp + 163840,  bb + 128, 64,  3, 9, 128 };
    ConvJob j3{ xb, qcat, wp + 311296,  bb + 192, 64,  6, 9, 192 };
    ConvJob j4{ xb, k1,   wp + 524288,  bb + 512, 256, 1, 9, 0   };
    ConvTable TA{ { ja, jb, j1, j2, j3, j4 }, { 512, 2560, 3072, 3584, 4096, 6144 } };
    conv_all<<<1536, 256, 0, stream>>>(TA);

    // dispatch B: q = 1x1(qcat, wq4), k = 3x3(k1, wk)  (4096 waves)
    ConvJob j5{ qcat, q, wp + 458752, bb + 256, 256, 1, 1, 0 };
    ConvJob j6{ k1,  kk, wp + 524288, bb + 512, 256, 1, 9, 0 };
    ConvTable TB{ { j5, j6, j6, j6, j6, j6 }, { 2048, 4096, 4096, 4096, 4096, 4096 } };
    conv_all<<<1024, 256, 0, stream>>>(TB);

    energy_mfma<<<512, 256, 0, stream>>>(q, kk, Et);
    softmax_k<<<1024, 256, 0, stream>>>(Et, att);
    out_mfma<<<512, 256, 0, stream>>>(vv, att, G);
    final_k<<<512, 256, 0, stream>>>(G, x, d_in[15], d_out, flag);
}